// Round 4
// baseline (2079.654 us; speedup 1.0000x reference)
//
#include <hip/hip_runtime.h>
#include <hip/hip_bf16.h>
#include <stdint.h>

// Problem constants (B=4, T=4096, D=2048); batch-serialized: R rows per batch
#define Dm  2048
#define Tt  4096
#define Bb  4
#define Rr  4096             // rows per pipeline pass (= Tt, one batch)
#define NCH 64               // scan chunks per batch
#define TCH 64               // timesteps per chunk
#define EPSf 1e-5f

typedef __attribute__((ext_vector_type(8))) short short8;
typedef __attribute__((ext_vector_type(4))) float f32x4;

__device__ __forceinline__ unsigned short f2bf(float x) {
  unsigned u = __builtin_bit_cast(unsigned, x);
  u += 0x7FFFu + ((u >> 16) & 1u);          // RNE
  return (unsigned short)(u >> 16);
}
__device__ __forceinline__ float bf2f(unsigned short b) {
  unsigned u = ((unsigned)b) << 16;
  return __builtin_bit_cast(float, u);
}
__device__ __forceinline__ float sigmoidf_(float x) {
  return 1.0f / (1.0f + __expf(-x));
}
__device__ __forceinline__ void gload16(const void* g, void* l) {
  __builtin_amdgcn_global_load_lds(
      (const __attribute__((address_space(1))) unsigned int*)g,
      (__attribute__((address_space(3))) unsigned int*)l, 16, 0, 0);
}

// ---------------- ws-too-small sentinel (diagnosable, no fault) ----------------
__global__ __launch_bounds__(256) void k_sentinel(float* __restrict__ out, int n) {
  int i = blockIdx.x * 256 + threadIdx.x;
  if (i < n) out[i] = 12345.0f;
}

// ---------------- fp32 -> bf16 hi/lo split ----------------
__global__ __launch_bounds__(256) void k_split(const float* __restrict__ in,
                                               short* __restrict__ hi,
                                               short* __restrict__ lo) {
  size_t i = (size_t)blockIdx.x * 256 + threadIdx.x;   // one group of 8 elems
  const float4* p = (const float4*)in + i * 2;
  float4 a = p[0], b = p[1];
  float v[8] = {a.x,a.y,a.z,a.w,b.x,b.y,b.z,b.w};
  short8 h, l;
#pragma unroll
  for (int j = 0; j < 8; ++j) {
    unsigned short hb = f2bf(v[j]);
    h[j] = (short)hb;
    l[j] = (short)f2bf(v[j] - bf2f(hb));
  }
  ((short8*)hi)[i] = h;
  ((short8*)lo)[i] = l;
}

// ---------- W [K][N] fp32  ->  Wt hi/lo [N][K] bf16 (transpose+split) ----------
__global__ __launch_bounds__(256) void k_convw(const float* __restrict__ W,
                                               short* __restrict__ hi,
                                               short* __restrict__ lo) {
  __shared__ float t[64][65];
  const int n0 = blockIdx.x * 64, k0 = blockIdx.y * 64;
  const int tid = threadIdx.x;
  const int r = tid >> 6, c = tid & 63;
#pragma unroll
  for (int rr = r; rr < 64; rr += 4)
    t[rr][c] = W[(size_t)(k0 + rr) * Dm + n0 + c];
  __syncthreads();
#pragma unroll
  for (int rr = r; rr < 64; rr += 4) {
    float v = t[c][rr];                       // = W[k0+c][n0+rr]
    unsigned short hb = f2bf(v);
    size_t o = (size_t)(n0 + rr) * Dm + k0 + c;
    hi[o] = (short)hb;
    lo[o] = (short)f2bf(v - bf2f(hb));
  }
}

// ---------------- bf16x3 split GEMM: C = A @ B,  Bt given as [N][K] ----------------
#define BM 128
#define BN 128
#define BK 32

__global__ __launch_bounds__(256, 2) void k_gemm(
    const short* __restrict__ Ah, const short* __restrict__ Al,
    const short* __restrict__ Bh, const short* __restrict__ Bl,
    float* __restrict__ C, int M, int N, int K) {
  __shared__ __align__(16) short sAh[BM*BK], sAl[BM*BK], sBh[BN*BK], sBl[BN*BK];
  const int tid  = threadIdx.x;
  const int lane = tid & 63;
  const int wave = tid >> 6;
  const int ntn  = N / BN;
  const int bx   = blockIdx.x % ntn;
  const int by   = blockIdx.x / ntn;
  const int m0 = by * BM, n0 = bx * BN;

  // staging: 512 16B-chunks per buffer, 2 per thread; XOR swizzle chunk^=(row>>1)&3,
  // applied on the GLOBAL source so the LDS dest stays lane-linear (rule #21).
  const int c0 = tid,        r0 = c0 >> 2, p0 = (c0 & 3) ^ ((r0 >> 1) & 3);
  const int c1 = tid + 256,  r1 = c1 >> 2, p1 = (c1 & 3) ^ ((r1 >> 1) & 3);
  const size_t ga0 = (size_t)(m0 + r0) * K + p0 * 8;
  const size_t ga1 = (size_t)(m0 + r1) * K + p1 * 8;
  const size_t gb0 = (size_t)(n0 + r0) * K + p0 * 8;
  const size_t gb1 = (size_t)(n0 + r1) * K + p1 * 8;

  const int wr = wave >> 1, wc = wave & 1;
  const int l15 = lane & 15, kg = lane >> 4;
  int aoff[4], boff[4];
#pragma unroll
  for (int f = 0; f < 4; ++f) {
    int ar = wr * 64 + f * 16 + l15;
    aoff[f] = ar * BK + (kg ^ ((ar >> 1) & 3)) * 8;
    int br = wc * 64 + f * 16 + l15;
    boff[f] = br * BK + (kg ^ ((br >> 1) & 3)) * 8;
  }

  f32x4 acc[4][4] = {};

  for (int kk = 0; kk < K; kk += BK) {
    gload16(Ah + ga0 + kk, sAh + c0 * 8);
    gload16(Ah + ga1 + kk, sAh + c1 * 8);
    gload16(Al + ga0 + kk, sAl + c0 * 8);
    gload16(Al + ga1 + kk, sAl + c1 * 8);
    gload16(Bh + gb0 + kk, sBh + c0 * 8);
    gload16(Bh + gb1 + kk, sBh + c1 * 8);
    gload16(Bl + gb0 + kk, sBl + c0 * 8);
    gload16(Bl + gb1 + kk, sBl + c1 * 8);
    __syncthreads();

    short8 ah[4], al[4], bh[4], bl[4];
#pragma unroll
    for (int f = 0; f < 4; ++f) {
      ah[f] = *(const short8*)(sAh + aoff[f]);
      al[f] = *(const short8*)(sAl + aoff[f]);
      bh[f] = *(const short8*)(sBh + boff[f]);
      bl[f] = *(const short8*)(sBl + boff[f]);
    }
    // three split-product passes; each acc touched once per pass (ILP-friendly)
#pragma unroll
    for (int mf = 0; mf < 4; ++mf)
#pragma unroll
      for (int nf = 0; nf < 4; ++nf)
        acc[mf][nf] = __builtin_amdgcn_mfma_f32_16x16x32_bf16(ah[mf], bh[nf], acc[mf][nf], 0, 0, 0);
#pragma unroll
    for (int mf = 0; mf < 4; ++mf)
#pragma unroll
      for (int nf = 0; nf < 4; ++nf)
        acc[mf][nf] = __builtin_amdgcn_mfma_f32_16x16x32_bf16(al[mf], bh[nf], acc[mf][nf], 0, 0, 0);
#pragma unroll
    for (int mf = 0; mf < 4; ++mf)
#pragma unroll
      for (int nf = 0; nf < 4; ++nf)
        acc[mf][nf] = __builtin_amdgcn_mfma_f32_16x16x32_bf16(ah[mf], bl[nf], acc[mf][nf], 0, 0, 0);
    __syncthreads();
  }

  // C/D layout: col = lane&15, row = (lane>>4)*4 + reg   [m89-verified]
#pragma unroll
  for (int mf = 0; mf < 4; ++mf)
#pragma unroll
    for (int nf = 0; nf < 4; ++nf) {
      const int crow = m0 + wr * 64 + mf * 16 + kg * 4;
      const int ccol = n0 + wc * 64 + nf * 16 + l15;
      float* cp = C + (size_t)crow * N + ccol;
#pragma unroll
      for (int r = 0; r < 4; ++r)
        cp[(size_t)r * N] = acc[mf][nf][r];
    }
}

// -------- chunked linear recurrence, one batch: h_t = a_t h_{t-1} + i_t --------
// pass 1: local scan; IN-PLACE: h overwrites i-raw, prefix-product P overwrites f-raw
__global__ __launch_bounds__(256) void k_scan1(float* __restrict__ fP,
                                               float* __restrict__ iH,
                                               float* __restrict__ Ps,
                                               float* __restrict__ Hs) {
  const int c = blockIdx.x;
  const int d = blockIdx.y * 256 + threadIdx.x;
  size_t idx = (size_t)c * TCH * Dm + d;
  float h = 0.f, P = 1.f;
  for (int t = 0; t < TCH; ++t, idx += Dm) {
    float f = fP[idx], iv = iH[idx];
    float a  = sigmoidf_(f);
    float ig = iv * sigmoidf_(iv) * (1.f - a);   // silu(i) * sigmoid(-f)
    h = __builtin_fmaf(a, h, ig);
    P *= a;
    iH[idx] = h;
    fP[idx] = P;                                 // save prefix prod for pass 3
  }
  size_t s = (size_t)c * Dm + d;
  Ps[s] = P;
  Hs[s] = h;
}

// pass 2: sequential combine of chunk summaries -> carry-in per chunk
__global__ __launch_bounds__(256) void k_scan2(const float* __restrict__ Ps,
                                               const float* __restrict__ Hs,
                                               float* __restrict__ cy) {
  const int d = blockIdx.x * 256 + threadIdx.x;  // 0..Dm-1
  float c = 0.f;
  for (int ch = 0; ch < NCH; ++ch) {
    size_t s = (size_t)ch * Dm + d;
    cy[s] = c;
    c = Hs[s] + Ps[s] * c;
  }
}

// pass 3: h_t += P_t * carry_in  (P_t precomputed by pass 1)
__global__ __launch_bounds__(256) void k_scan3(const float* __restrict__ fP,
                                               float* __restrict__ oH,
                                               const float* __restrict__ cyb) {
  const int c = blockIdx.x;
  const int d = blockIdx.y * 256 + threadIdx.x;
  size_t s = (size_t)c * Dm + d;
  float cy = cyb[s];
  if (__all(cy == 0.f)) return;                 // chunk 0 fast-path
  size_t idx = (size_t)c * TCH * Dm + d;
  for (int t = 0; t < TCH; ++t, idx += Dm)
    oH[idx] = __builtin_fmaf(fP[idx], cy, oH[idx]);
}

// --------- RMSNorm * weight * (g*sigmoid(g)), fused with bf16 hi/lo split ---------
__global__ __launch_bounds__(256) void k_norm(const float* __restrict__ o,
                                              const float* __restrict__ g,
                                              const float* __restrict__ gw,
                                              short* __restrict__ oh,
                                              short* __restrict__ ol) {
  const int row = blockIdx.x;
  const size_t base = (size_t)row * Dm;
  const int tid = threadIdx.x;
  const float4* po = (const float4*)(o + base) + tid * 2;
  float4 o0 = po[0], o1 = po[1];
  float ss = o0.x*o0.x + o0.y*o0.y + o0.z*o0.z + o0.w*o0.w
           + o1.x*o1.x + o1.y*o1.y + o1.z*o1.z + o1.w*o1.w;
#pragma unroll
  for (int off = 32; off > 0; off >>= 1) ss += __shfl_down(ss, off, 64);
  __shared__ float red[4];
  if ((tid & 63) == 0) red[tid >> 6] = ss;
  __syncthreads();
  const float rms = rsqrtf((red[0] + red[1] + red[2] + red[3]) * (1.0f / Dm) + EPSf);
  const float4* pg = (const float4*)(g + base) + tid * 2;
  float4 g0 = pg[0], g1 = pg[1];
  const float4* pw = (const float4*)gw + tid * 2;
  float4 w0 = pw[0], w1 = pw[1];
  float ov[8] = {o0.x,o0.y,o0.z,o0.w,o1.x,o1.y,o1.z,o1.w};
  float gv[8] = {g0.x,g0.y,g0.z,g0.w,g1.x,g1.y,g1.z,g1.w};
  float wv[8] = {w0.x,w0.y,w0.z,w0.w,w1.x,w1.y,w1.z,w1.w};
  short8 h8, l8;
#pragma unroll
  for (int j = 0; j < 8; ++j) {
    float val = ov[j] * rms * wv[j] * (gv[j] * sigmoidf_(gv[j]));
    unsigned short hb = f2bf(val);
    h8[j] = (short)hb;
    l8[j] = (short)f2bf(val - bf2f(hb));
  }
  ((short8*)(oh + base))[tid] = h8;
  ((short8*)(ol + base))[tid] = l8;
}

// ------------------------------- launcher -------------------------------
extern "C" void kernel_launch(void* const* d_in, const int* in_sizes, int n_in,
                              void* d_out, int out_size, void* d_ws, size_t ws_size,
                              hipStream_t stream) {
  const float* x   = (const float*)d_in[0];
  const float* Wi  = (const float*)d_in[1];
  const float* Wf  = (const float*)d_in[2];
  const float* Wg  = (const float*)d_in[3];
  const float* Wo  = (const float*)d_in[4];
  const float* gnw = (const float*)d_in[5];
  float* out = (float*)d_out;
  char* ws = (char*)d_ws;

  // lean workspace layout (batch-serialized): ~194 MiB total
  const size_t WOFF = 0;                        // 8 x 8 MB bf16 weight splits
  const size_t XHI  = 67108864ULL;              // 16 MB  (o2_hi overlay after norm)
  const size_t XLO  = 83886080ULL;              // 16 MB  (o2_lo overlay)
  const size_t GI   = 100663296ULL;             // 32 MB  i-raw -> h
  const size_t GF   = 134217728ULL;             // 32 MB  f-raw -> prefix P
  const size_t GG   = 167772160ULL;             // 32 MB  g-raw
  const size_t PS   = 201326592ULL;             // 512 KB
  const size_t HS   = 201850880ULL;             // 512 KB
  const size_t CY   = 202375168ULL;             // 512 KB
  const size_t NEED = 202899456ULL;

  if (ws_size < NEED) {                         // diagnosable fallback, no fault
    k_sentinel<<<(out_size + 255) / 256, 256, 0, stream>>>(out, out_size);
    return;
  }

  short* x_hi = (short*)(ws + XHI);
  short* x_lo = (short*)(ws + XLO);
  float* gi   = (float*)(ws + GI);
  float* gf   = (float*)(ws + GF);
  float* gg   = (float*)(ws + GG);
  float* Psum = (float*)(ws + PS);
  float* Hsum = (float*)(ws + HS);
  float* carry= (float*)(ws + CY);

  short* wbuf = (short*)(ws + WOFF);
  const size_t WSZ = (size_t)Dm * Dm;           // shorts per matrix
  short* Wih = wbuf + 0 * WSZ; short* Wil = wbuf + 1 * WSZ;
  short* Wfh = wbuf + 2 * WSZ; short* Wfl = wbuf + 3 * WSZ;
  short* Wgh = wbuf + 4 * WSZ; short* Wgl = wbuf + 5 * WSZ;
  short* Woh = wbuf + 6 * WSZ; short* Wol = wbuf + 7 * WSZ;

  // weight transpose+split, once
  dim3 gwt(Dm / 64, Dm / 64);
  k_convw<<<gwt, 256, 0, stream>>>(Wi, Wih, Wil);
  k_convw<<<gwt, 256, 0, stream>>>(Wf, Wfh, Wfl);
  k_convw<<<gwt, 256, 0, stream>>>(Wg, Wgh, Wgl);
  k_convw<<<gwt, 256, 0, stream>>>(Wo, Woh, Wol);

  const int gblocks = (Rr / BM) * (Dm / BN);    // 512
  const dim3 gsc(NCH, Dm / 256);                // 64 x 8

  for (int b = 0; b < Bb; ++b) {                // scan is per-batch: fully independent
    const size_t rowoff = (size_t)b * Rr * Dm;

    k_split<<<(Rr * Dm / 8) / 256, 256, 0, stream>>>(x + rowoff, x_hi, x_lo);

    k_gemm<<<gblocks, 256, 0, stream>>>(x_hi, x_lo, Wih, Wil, gi, Rr, Dm, Dm);
    k_gemm<<<gblocks, 256, 0, stream>>>(x_hi, x_lo, Wfh, Wfl, gf, Rr, Dm, Dm);
    k_gemm<<<gblocks, 256, 0, stream>>>(x_hi, x_lo, Wgh, Wgl, gg, Rr, Dm, Dm);

    k_scan1<<<gsc, 256, 0, stream>>>(gf, gi, Psum, Hsum);
    k_scan2<<<Dm / 256, 256, 0, stream>>>(Psum, Hsum, carry);
    k_scan3<<<gsc, 256, 0, stream>>>(gf, gi, carry);

    k_norm<<<Rr, 256, 0, stream>>>(gi, gg, gnw, x_hi, x_lo);   // overwrite x split

    k_gemm<<<gblocks, 256, 0, stream>>>(x_hi, x_lo, Woh, Wol, out + rowoff, Rr, Dm, Dm);
  }
}